// Round 2
// baseline (254.809 us; speedup 1.0000x reference)
//
#include <hip/hip_runtime.h>
#include <hip/hip_bf16.h>

#define S_  384
#define H_  256
#define NH_ 8
#define DH_ 32
#define B_  4
#define PADK 385

// ---------------- Kernel P: fused QKV projections ----------------
// grid (48, 4, 3), block 256. Tile 32(m) x 64(n), K-tile 32.
__global__ __launch_bounds__(256) void proj_kernel(
    const float* __restrict__ query, const float* __restrict__ key, const float* __restrict__ value,
    const float* __restrict__ Wq, const float* __restrict__ bq,
    const float* __restrict__ Wk, const float* __restrict__ bk,
    const float* __restrict__ Wv, const float* __restrict__ bv,
    float* __restrict__ Qb, float* __restrict__ Kb, float* __restrict__ Vb)
{
    __shared__ __align__(16) float As[32][36];
    __shared__ __align__(16) float Bs[32][68];
    const int t = threadIdx.x;
    const int m0g = blockIdx.x * 32;
    const int n0g = blockIdx.y * 64;
    const int z = blockIdx.z;
    const float* X    = (z == 0) ? query : (z == 1 ? key : value);
    const float* W    = (z == 0) ? Wq    : (z == 1 ? Wk  : Wv);
    const float* bias = (z == 0) ? bq    : (z == 1 ? bk  : bv);
    float* Out        = (z == 0) ? Qb    : (z == 1 ? Kb  : Vb);

    const int tn = (t & 15) * 4;      // 4 output cols
    const int tm = (t >> 4) * 2;      // 2 output rows
    float acc0[4] = {0.f,0.f,0.f,0.f};
    float acc1[4] = {0.f,0.f,0.f,0.f};

    const int ar = t >> 3, ac4 = (t & 7) * 4;     // A staging: 32 rows x 32 cols
    const int brr = t >> 4, bc4 = (t & 15) * 4;   // B staging: 32 rows x 64 cols

    for (int kt = 0; kt < 8; ++kt) {
        const int k0 = kt * 32;
        float4 av  = *(const float4*)&X[(size_t)(m0g + ar) * H_ + k0 + ac4];
        float4 bv0 = *(const float4*)&W[(size_t)(k0 + brr)      * H_ + n0g + bc4];
        float4 bv1 = *(const float4*)&W[(size_t)(k0 + brr + 16) * H_ + n0g + bc4];
        *(float4*)&As[ar][ac4] = av;
        *(float4*)&Bs[brr][bc4] = bv0;
        *(float4*)&Bs[brr + 16][bc4] = bv1;
        __syncthreads();
        #pragma unroll
        for (int c = 0; c < 32; ++c) {
            const float a0 = As[tm][c], a1 = As[tm + 1][c];
            const float4 b4 = *(const float4*)&Bs[c][tn];
            acc0[0] += a0 * b4.x; acc0[1] += a0 * b4.y; acc0[2] += a0 * b4.z; acc0[3] += a0 * b4.w;
            acc1[0] += a1 * b4.x; acc1[1] += a1 * b4.y; acc1[2] += a1 * b4.z; acc1[3] += a1 * b4.w;
        }
        __syncthreads();
    }
    const float4 bi = *(const float4*)&bias[n0g + tn];
    float4 o0 = make_float4(acc0[0] + bi.x, acc0[1] + bi.y, acc0[2] + bi.z, acc0[3] + bi.w);
    float4 o1 = make_float4(acc1[0] + bi.x, acc1[1] + bi.y, acc1[2] + bi.z, acc1[3] + bi.w);
    *(float4*)&Out[(size_t)(m0g + tm)     * H_ + n0g + tn] = o0;
    *(float4*)&Out[(size_t)(m0g + tm + 1) * H_ + n0g + tn] = o1;
}

// ---------------- Kernel QW: qW[b,q,h,e] = sum_d Q[b,q,hd]*Wr[e,hd]; qb = Q . br ----
// grid (96, 8), block 256 (thread = e).
__global__ __launch_bounds__(256) void qw_kernel(
    const float* __restrict__ Qb, const float* __restrict__ Wr, const float* __restrict__ br,
    float* __restrict__ qW, float* __restrict__ qb)
{
    __shared__ __align__(16) float Qs[16][36];
    const int t = threadIdx.x;                // e index
    const int m0 = blockIdx.x * 16;           // row block over b*S+q
    const int h = blockIdx.y;

    float4 wr4[8];
    #pragma unroll
    for (int j = 0; j < 8; ++j)
        wr4[j] = *(const float4*)&Wr[(size_t)t * H_ + h * DH_ + j * 4];

    if (t < 128) {
        const int r = t >> 3, d4 = (t & 7) * 4;
        *(float4*)&Qs[r][d4] = *(const float4*)&Qb[(size_t)(m0 + r) * H_ + h * DH_ + d4];
    }
    __syncthreads();

    #pragma unroll 4
    for (int r = 0; r < 16; ++r) {
        float acc = 0.f;
        #pragma unroll
        for (int j = 0; j < 8; ++j) {
            const float4 qv = *(const float4*)&Qs[r][j * 4];
            acc += qv.x * wr4[j].x + qv.y * wr4[j].y + qv.z * wr4[j].z + qv.w * wr4[j].w;
        }
        qW[(size_t)((m0 + r) * NH_ + h) * H_ + t] = acc;
    }
    if (t < 16) {
        float s = 0.f;
        #pragma unroll
        for (int d = 0; d < 32; ++d) s += Qs[t][d] * br[h * DH_ + d];
        qb[(m0 + t) * NH_ + h] = s;
    }
}

// ---------------- Kernel B: fused scores + mask + softmax + PV ----------------
// grid 1536 (one WG per (b,q), batch-interleaved), block 256 = 4 waves.
// Lane ownership in phase 1: lane = hl*8 + c  (hl = head, c = 4-float e-chunk).
// qW slices live in registers; reduction is only a 3-round xor over c.
__global__ __launch_bounds__(256) void attn_kernel(
    const float* __restrict__ rpe, const float* __restrict__ Qb, const float* __restrict__ Kb,
    const float* __restrict__ Vb, const float* __restrict__ qW, const float* __restrict__ qb,
    const int* __restrict__ seq_len, const int* __restrict__ lex_num,
    float* __restrict__ out)
{
    __shared__ float sc[NH_ * PADK];
    const int blk = blockIdx.x;
    const int b = blk & 3;           // batch-interleaved for load balance
    const int q = blk >> 2;
    const int t = threadIdx.x;
    const int lane = t & 63;
    const int wave = t >> 6;
    int limit = seq_len[b] + lex_num[b];
    limit = limit < 0 ? 0 : (limit > S_ ? S_ : limit);
    const size_t rowQ = (size_t)(b * S_ + q);

    if (limit == 0) {
        // all keys masked -> softmax over uniform -1e15 -> exactly 1/S each
        float acc = 0.f;
        const float* vb = Vb + (size_t)b * S_ * H_ + t;
        for (int k = 0; k < S_; ++k) acc += vb[(size_t)k * H_];
        out[rowQ * H_ + t] = acc * (1.0f / S_);
        return;
    }

    const int hl = lane >> 3;   // head owned by this lane
    const int c  = lane & 7;    // 4-float e-chunk within each 32-e subtile

    // qW[hl] register slices: j-th covers e = c*4 + j*32
    float4 qw4[8];
    #pragma unroll
    for (int j = 0; j < 8; ++j)
        qw4[j] = *(const float4*)&qW[(rowQ * NH_ + hl) * H_ + c * 4 + j * 32];
    // Q slice for A_C (only head hl's 32 dims matter): e = hl*32 + c*4
    const float4 qk4 = *(const float4*)&Qb[rowQ * H_ + hl * 32 + c * 4];
    const float qbv = qb[rowQ * NH_ + hl];

    const float* rpe_base = rpe + rowQ * (size_t)S_ * H_;
    const float* K_base = Kb + (size_t)b * S_ * H_;

    #pragma unroll 2
    for (int k = wave; k < limit; k += 4) {
        const float* rpe_row = rpe_base + (size_t)k * H_;
        // issue all loads first
        float4 r4[8];
        #pragma unroll
        for (int j = 0; j < 8; ++j)
            r4[j] = *(const float4*)&rpe_row[c * 4 + j * 32];
        const float4 k4 = *(const float4*)&K_base[(size_t)k * H_ + hl * 32 + c * 4];

        float f0 = 0.f, f1 = 0.f;   // two chains for ILP
        #pragma unroll
        for (int j = 0; j < 8; j += 2) {
            f0 += r4[j].x * qw4[j].x + r4[j].y * qw4[j].y + r4[j].z * qw4[j].z + r4[j].w * qw4[j].w;
            f1 += r4[j+1].x * qw4[j+1].x + r4[j+1].y * qw4[j+1].y + r4[j+1].z * qw4[j+1].z + r4[j+1].w * qw4[j+1].w;
        }
        float s = f0 + f1
                + k4.x * qk4.x + k4.y * qk4.y + k4.z * qk4.z + k4.w * qk4.w;
        // reduce over the 8 c-lanes (same head)
        s += __shfl_xor(s, 1, 64);
        s += __shfl_xor(s, 2, 64);
        s += __shfl_xor(s, 4, 64);
        if (c == 0) sc[hl * PADK + k] = s + qbv;
    }
    __syncthreads();

    // ---- softmax: wave w owns heads 2w, 2w+1 ----
    for (int hh = 0; hh < 2; ++hh) {
        const int h = wave * 2 + hh;
        float s0[6];
        #pragma unroll
        for (int j = 0; j < 6; ++j) {
            const int k = lane + 64 * j;
            s0[j] = (k < limit) ? sc[h * PADK + k] : -1e15f;
        }
        float mx = s0[0];
        #pragma unroll
        for (int j = 1; j < 6; ++j) mx = fmaxf(mx, s0[j]);
        #pragma unroll
        for (int m = 1; m < 64; m <<= 1) mx = fmaxf(mx, __shfl_xor(mx, m, 64));
        float p[6]; float sum = 0.f;
        #pragma unroll
        for (int j = 0; j < 6; ++j) {
            const int k = lane + 64 * j;
            p[j] = (k < limit) ? __expf(s0[j] - mx) : 0.f;
            sum += p[j];
        }
        #pragma unroll
        for (int m = 1; m < 64; m <<= 1) sum += __shfl_xor(sum, m, 64);
        const float inv = 1.0f / sum;
        #pragma unroll
        for (int j = 0; j < 6; ++j) sc[h * PADK + lane + 64 * j] = p[j] * inv;
    }
    __syncthreads();

    // ---- PV: thread t -> (h = t>>5, d = t&31), serial over k ----
    {
        const int h = t >> 5;
        const int d = t & 31;
        const float* vcol = Vb + (size_t)b * S_ * H_ + h * DH_ + d;
        const float* prow = &sc[h * PADK];
        float acc = 0.f;
        int k = 0;
        for (; k + 8 <= limit; k += 8) {
            float vv[8], pp[8];
            #pragma unroll
            for (int u = 0; u < 8; ++u) vv[u] = vcol[(size_t)(k + u) * H_];
            #pragma unroll
            for (int u = 0; u < 8; ++u) pp[u] = prow[k + u];
            #pragma unroll
            for (int u = 0; u < 8; ++u) acc += pp[u] * vv[u];
        }
        for (; k < limit; ++k) acc += prow[k] * vcol[(size_t)k * H_];
        out[rowQ * H_ + h * DH_ + d] = acc;
    }
}

extern "C" void kernel_launch(void* const* d_in, const int* in_sizes, int n_in,
                              void* d_out, int out_size, void* d_ws, size_t ws_size,
                              hipStream_t stream)
{
    const float* key   = (const float*)d_in[0];
    const float* query = (const float*)d_in[1];
    const float* value = (const float*)d_in[2];
    const float* rpe   = (const float*)d_in[3];
    const int* seq_len = (const int*)d_in[4];
    const int* lex_num = (const int*)d_in[5];
    const float* Wk = (const float*)d_in[6];
    const float* bk = (const float*)d_in[7];
    const float* Wq = (const float*)d_in[8];
    const float* bq = (const float*)d_in[9];
    const float* Wv = (const float*)d_in[10];
    const float* bv = (const float*)d_in[11];
    const float* Wr = (const float*)d_in[12];
    const float* br = (const float*)d_in[13];

    float* w = (float*)d_ws;
    float* Qb = w;
    float* Kb = Qb + (size_t)B_ * S_ * H_;
    float* Vb = Kb + (size_t)B_ * S_ * H_;
    float* qW = Vb + (size_t)B_ * S_ * H_;
    float* qb = qW + (size_t)B_ * S_ * NH_ * H_;

    proj_kernel<<<dim3(48, 4, 3), dim3(256), 0, stream>>>(
        query, key, value, Wq, bq, Wk, bk, Wv, bv, Qb, Kb, Vb);
    qw_kernel<<<dim3(96, 8), dim3(256), 0, stream>>>(Qb, Wr, br, qW, qb);
    attn_kernel<<<dim3(1536), dim3(256), 0, stream>>>(
        rpe, Qb, Kb, Vb, qW, qb, seq_len, lex_num, (float*)d_out);
}

// Round 3
// 159.582 us; speedup vs baseline: 1.5967x; 1.5967x over previous
//
#include <hip/hip_runtime.h>
#include <hip/hip_bf16.h>

#define S_  384
#define H_  256
#define NH_ 8
#define DH_ 32
#define B_  4
#define PADK 385

// ---------------- Kernel P: fused QKV projections ----------------
__global__ __launch_bounds__(256) void proj_kernel(
    const float* __restrict__ query, const float* __restrict__ key, const float* __restrict__ value,
    const float* __restrict__ Wq, const float* __restrict__ bq,
    const float* __restrict__ Wk, const float* __restrict__ bk,
    const float* __restrict__ Wv, const float* __restrict__ bv,
    float* __restrict__ Qb, float* __restrict__ Kb, float* __restrict__ Vb)
{
    __shared__ __align__(16) float As[32][36];
    __shared__ __align__(16) float Bs[32][68];
    const int t = threadIdx.x;
    const int m0g = blockIdx.x * 32;
    const int n0g = blockIdx.y * 64;
    const int z = blockIdx.z;
    const float* X    = (z == 0) ? query : (z == 1 ? key : value);
    const float* W    = (z == 0) ? Wq    : (z == 1 ? Wk  : Wv);
    const float* bias = (z == 0) ? bq    : (z == 1 ? bk  : bv);
    float* Out        = (z == 0) ? Qb    : (z == 1 ? Kb  : Vb);

    const int tn = (t & 15) * 4;
    const int tm = (t >> 4) * 2;
    float acc0[4] = {0.f,0.f,0.f,0.f};
    float acc1[4] = {0.f,0.f,0.f,0.f};

    const int ar = t >> 3, ac4 = (t & 7) * 4;
    const int brr = t >> 4, bc4 = (t & 15) * 4;

    for (int kt = 0; kt < 8; ++kt) {
        const int k0 = kt * 32;
        float4 av  = *(const float4*)&X[(size_t)(m0g + ar) * H_ + k0 + ac4];
        float4 bv0 = *(const float4*)&W[(size_t)(k0 + brr)      * H_ + n0g + bc4];
        float4 bv1 = *(const float4*)&W[(size_t)(k0 + brr + 16) * H_ + n0g + bc4];
        *(float4*)&As[ar][ac4] = av;
        *(float4*)&Bs[brr][bc4] = bv0;
        *(float4*)&Bs[brr + 16][bc4] = bv1;
        __syncthreads();
        #pragma unroll
        for (int c = 0; c < 32; ++c) {
            const float a0 = As[tm][c], a1 = As[tm + 1][c];
            const float4 b4 = *(const float4*)&Bs[c][tn];
            acc0[0] += a0 * b4.x; acc0[1] += a0 * b4.y; acc0[2] += a0 * b4.z; acc0[3] += a0 * b4.w;
            acc1[0] += a1 * b4.x; acc1[1] += a1 * b4.y; acc1[2] += a1 * b4.z; acc1[3] += a1 * b4.w;
        }
        __syncthreads();
    }
    const float4 bi = *(const float4*)&bias[n0g + tn];
    float4 o0 = make_float4(acc0[0] + bi.x, acc0[1] + bi.y, acc0[2] + bi.z, acc0[3] + bi.w);
    float4 o1 = make_float4(acc1[0] + bi.x, acc1[1] + bi.y, acc1[2] + bi.z, acc1[3] + bi.w);
    *(float4*)&Out[(size_t)(m0g + tm)     * H_ + n0g + tn] = o0;
    *(float4*)&Out[(size_t)(m0g + tm + 1) * H_ + n0g + tn] = o1;
}

// ---------------- Kernel QW ----------------
__global__ __launch_bounds__(256) void qw_kernel(
    const float* __restrict__ Qb, const float* __restrict__ Wr, const float* __restrict__ br,
    float* __restrict__ qW, float* __restrict__ qb)
{
    __shared__ __align__(16) float Qs[16][36];
    const int t = threadIdx.x;
    const int m0 = blockIdx.x * 16;
    const int h = blockIdx.y;

    float4 wr4[8];
    #pragma unroll
    for (int j = 0; j < 8; ++j)
        wr4[j] = *(const float4*)&Wr[(size_t)t * H_ + h * DH_ + j * 4];

    if (t < 128) {
        const int r = t >> 3, d4 = (t & 7) * 4;
        *(float4*)&Qs[r][d4] = *(const float4*)&Qb[(size_t)(m0 + r) * H_ + h * DH_ + d4];
    }
    __syncthreads();

    #pragma unroll 4
    for (int r = 0; r < 16; ++r) {
        float acc = 0.f;
        #pragma unroll
        for (int j = 0; j < 8; ++j) {
            const float4 qv = *(const float4*)&Qs[r][j * 4];
            acc += qv.x * wr4[j].x + qv.y * wr4[j].y + qv.z * wr4[j].z + qv.w * wr4[j].w;
        }
        qW[(size_t)((m0 + r) * NH_ + h) * H_ + t] = acc;
    }
    if (t < 16) {
        float s = 0.f;
        #pragma unroll
        for (int d = 0; d < 32; ++d) s += Qs[t][d] * br[h * DH_ + d];
        qb[(m0 + t) * NH_ + h] = s;
    }
}

// ---------------- Kernel B: fused scores + mask + softmax + PV ----------------
// Round-1 coalesced layout (lane = e-chunk, 1KB row loads), but:
//  - A_C folded into the butterfly via loop-invariant selects (no ac tree/bpermute)
//  - two k-rows per iteration -> two independent reduction chains in flight
__global__ __launch_bounds__(256) void attn_kernel(
    const float* __restrict__ rpe, const float* __restrict__ Qb, const float* __restrict__ Kb,
    const float* __restrict__ Vb, const float* __restrict__ qW, const float* __restrict__ qb,
    const int* __restrict__ seq_len, const int* __restrict__ lex_num,
    float* __restrict__ out)
{
    __shared__ float sc[NH_ * PADK];
    const int blk = blockIdx.x;
    const int b = blk / S_;
    const int q = blk - b * S_;
    const int t = threadIdx.x;
    const int lane = t & 63;
    const int wave = t >> 6;
    int limit = seq_len[b] + lex_num[b];
    limit = limit < 0 ? 0 : (limit > S_ ? S_ : limit);
    const size_t rowQ = (size_t)(b * S_ + q);

    if (limit == 0) {
        float acc = 0.f;
        const float* vb = Vb + (size_t)b * S_ * H_ + t;
        for (int k = 0; k < S_; ++k) acc += vb[(size_t)k * H_];
        out[rowQ * H_ + t] = acc * (1.0f / S_);
        return;
    }

    const int hl = lane >> 3;                                   // head of this lane's e-chunk
    const int hrev = ((lane & 1) << 2) | (lane & 2) | ((lane >> 2) & 1);

    float4 qw4[NH_];
    #pragma unroll
    for (int h = 0; h < NH_; ++h)
        qw4[h] = *(const float4*)&qW[(rowQ * NH_ + h) * H_ + lane * 4];
    const float4 qk4 = *(const float4*)&Qb[rowQ * H_ + lane * 4];
    const float qbv = qb[rowQ * NH_ + hrev];

    const float* rpe_base = rpe + rowQ * (size_t)S_ * H_;
    const float* K_base = Kb + (size_t)b * S_ * H_;

    for (int kk = wave; kk < limit; kk += 8) {
        const int kA = kk;
        const int kB = kk + 4;
        const int kBl = (kB < limit) ? kB : (limit - 1);
        // issue all 4 coalesced 1KB loads up front
        const float4 rA = *(const float4*)&rpe_base[(size_t)kA  * H_ + lane * 4];
        const float4 kA4 = *(const float4*)&K_base [(size_t)kA  * H_ + lane * 4];
        const float4 rB = *(const float4*)&rpe_base[(size_t)kBl * H_ + lane * 4];
        const float4 kB4 = *(const float4*)&K_base [(size_t)kBl * H_ + lane * 4];

        float fa[NH_], fb[NH_];
        #pragma unroll
        for (int h = 0; h < NH_; ++h) {
            fa[h] = rA.x * qw4[h].x + rA.y * qw4[h].y + rA.z * qw4[h].z + rA.w * qw4[h].w;
            fb[h] = rB.x * qw4[h].x + rB.y * qw4[h].y + rB.z * qw4[h].z + rB.w * qw4[h].w;
        }
        const float acvA = kA4.x * qk4.x + kA4.y * qk4.y + kA4.z * qk4.z + kA4.w * qk4.w;
        const float acvB = kB4.x * qk4.x + kB4.y * qk4.y + kB4.z * qk4.z + kB4.w * qk4.w;
        #pragma unroll
        for (int h = 0; h < NH_; ++h) {
            fa[h] += (hl == h) ? acvA : 0.0f;   // loop-invariant compare -> cndmask
            fb[h] += (hl == h) ? acvB : 0.0f;
        }

        // butterfly reduce both sets (independent chains, interleaved by scheduler)
        {   const bool hi = (lane & 1) != 0;
            #pragma unroll
            for (int i = 0; i < 4; ++i) {
                const float sA = hi ? fa[i] : fa[i + 4];
                const float kApart = hi ? fa[i + 4] : fa[i];
                const float sB = hi ? fb[i] : fb[i + 4];
                const float kBpart = hi ? fb[i + 4] : fb[i];
                fa[i] = kApart + __shfl_xor(sA, 1, 64);
                fb[i] = kBpart + __shfl_xor(sB, 1, 64);
            }
        }
        {   const bool hi = (lane & 2) != 0;
            #pragma unroll
            for (int i = 0; i < 2; ++i) {
                const float sA = hi ? fa[i] : fa[i + 2];
                const float kApart = hi ? fa[i + 2] : fa[i];
                const float sB = hi ? fb[i] : fb[i + 2];
                const float kBpart = hi ? fb[i + 2] : fb[i];
                fa[i] = kApart + __shfl_xor(sA, 2, 64);
                fb[i] = kBpart + __shfl_xor(sB, 2, 64);
            }
        }
        {   const bool hi = (lane & 4) != 0;
            const float sA = hi ? fa[0] : fa[1];
            const float kApart = hi ? fa[1] : fa[0];
            const float sB = hi ? fb[0] : fb[1];
            const float kBpart = hi ? fb[1] : fb[0];
            fa[0] = kApart + __shfl_xor(sA, 4, 64);
            fb[0] = kBpart + __shfl_xor(sB, 4, 64);
        }
        fa[0] += __shfl_xor(fa[0], 8, 64);
        fb[0] += __shfl_xor(fb[0], 8, 64);
        fa[0] += __shfl_xor(fa[0], 16, 64);
        fb[0] += __shfl_xor(fb[0], 16, 64);
        fa[0] += __shfl_xor(fa[0], 32, 64);
        fb[0] += __shfl_xor(fb[0], 32, 64);

        if (lane < 8) {
            sc[hrev * PADK + kA] = fa[0] + qbv;
            if (kB < limit) sc[hrev * PADK + kB] = fb[0] + qbv;
        }
    }
    __syncthreads();

    // ---- softmax: wave w owns heads 2w, 2w+1 ----
    for (int hh = 0; hh < 2; ++hh) {
        const int h = wave * 2 + hh;
        float s0[6];
        #pragma unroll
        for (int j = 0; j < 6; ++j) {
            const int k = lane + 64 * j;
            s0[j] = (k < limit) ? sc[h * PADK + k] : -1e15f;
        }
        float mx = s0[0];
        #pragma unroll
        for (int j = 1; j < 6; ++j) mx = fmaxf(mx, s0[j]);
        #pragma unroll
        for (int m = 1; m < 64; m <<= 1) mx = fmaxf(mx, __shfl_xor(mx, m, 64));
        float p[6]; float sum = 0.f;
        #pragma unroll
        for (int j = 0; j < 6; ++j) {
            const int k = lane + 64 * j;
            p[j] = (k < limit) ? __expf(s0[j] - mx) : 0.f;
            sum += p[j];
        }
        #pragma unroll
        for (int m = 1; m < 64; m <<= 1) sum += __shfl_xor(sum, m, 64);
        const float inv = 1.0f / sum;
        #pragma unroll
        for (int j = 0; j < 6; ++j) sc[h * PADK + lane + 64 * j] = p[j] * inv;
    }
    __syncthreads();

    // ---- PV: thread t -> (h = t>>5, d = t&31), serial over k ----
    {
        const int h = t >> 5;
        const int d = t & 31;
        const float* vcol = Vb + (size_t)b * S_ * H_ + h * DH_ + d;
        const float* prow = &sc[h * PADK];
        float acc = 0.f;
        int k = 0;
        for (; k + 8 <= limit; k += 8) {
            float vv[8], pp[8];
            #pragma unroll
            for (int u = 0; u < 8; ++u) vv[u] = vcol[(size_t)(k + u) * H_];
            #pragma unroll
            for (int u = 0; u < 8; ++u) pp[u] = prow[k + u];
            #pragma unroll
            for (int u = 0; u < 8; ++u) acc += pp[u] * vv[u];
        }
        for (; k < limit; ++k) acc += prow[k] * vcol[(size_t)k * H_];
        out[rowQ * H_ + h * DH_ + d] = acc;
    }
}

extern "C" void kernel_launch(void* const* d_in, const int* in_sizes, int n_in,
                              void* d_out, int out_size, void* d_ws, size_t ws_size,
                              hipStream_t stream)
{
    const float* key   = (const float*)d_in[0];
    const float* query = (const float*)d_in[1];
    const float* value = (const float*)d_in[2];
    const float* rpe   = (const float*)d_in[3];
    const int* seq_len = (const int*)d_in[4];
    const int* lex_num = (const int*)d_in[5];
    const float* Wk = (const float*)d_in[6];
    const float* bk = (const float*)d_in[7];
    const float* Wq = (const float*)d_in[8];
    const float* bq = (const float*)d_in[9];
    const float* Wv = (const float*)d_in[10];
    const float* bv = (const float*)d_in[11];
    const float* Wr = (const float*)d_in[12];
    const float* br = (const float*)d_in[13];

    float* w = (float*)d_ws;
    float* Qb = w;
    float* Kb = Qb + (size_t)B_ * S_ * H_;
    float* Vb = Kb + (size_t)B_ * S_ * H_;
    float* qW = Vb + (size_t)B_ * S_ * H_;
    float* qb = qW + (size_t)B_ * S_ * NH_ * H_;

    proj_kernel<<<dim3(48, 4, 3), dim3(256), 0, stream>>>(
        query, key, value, Wq, bq, Wk, bk, Wv, bv, Qb, Kb, Vb);
    qw_kernel<<<dim3(96, 8), dim3(256), 0, stream>>>(Qb, Wr, br, qW, qb);
    attn_kernel<<<dim3(1536), dim3(256), 0, stream>>>(
        rpe, Qb, Kb, Vb, qW, qb, seq_len, lex_num, (float*)d_out);
}

// Round 4
// 138.246 us; speedup vs baseline: 1.8432x; 1.1543x over previous
//
#include <hip/hip_runtime.h>
#include <hip/hip_bf16.h>

#define S_  384
#define H_  256
#define NH_ 8
#define DH_ 32
#define B_  4
#define PADK 385

typedef _Float16 f16x8 __attribute__((ext_vector_type(8)));
typedef _Float16 f16x4 __attribute__((ext_vector_type(4)));
typedef float    f32x4 __attribute__((ext_vector_type(4)));

// ---------------- Kernel P: fused QKV projections ----------------
// z==0 -> Qb (f32), z==1 -> Kf (f16), z==2 -> Vb (f32)
__global__ __launch_bounds__(256) void proj_kernel(
    const float* __restrict__ query, const float* __restrict__ key, const float* __restrict__ value,
    const float* __restrict__ Wq, const float* __restrict__ bq,
    const float* __restrict__ Wk, const float* __restrict__ bk,
    const float* __restrict__ Wv, const float* __restrict__ bv,
    float* __restrict__ Qb, _Float16* __restrict__ Kf, float* __restrict__ Vb)
{
    __shared__ __align__(16) float As[32][36];
    __shared__ __align__(16) float Bs[32][68];
    const int t = threadIdx.x;
    const int m0g = blockIdx.x * 32;
    const int n0g = blockIdx.y * 64;
    const int z = blockIdx.z;
    const float* X    = (z == 0) ? query : (z == 1 ? key : value);
    const float* W    = (z == 0) ? Wq    : (z == 1 ? Wk  : Wv);
    const float* bias = (z == 0) ? bq    : (z == 1 ? bk  : bv);

    const int tn = (t & 15) * 4;
    const int tm = (t >> 4) * 2;
    float acc0[4] = {0.f,0.f,0.f,0.f};
    float acc1[4] = {0.f,0.f,0.f,0.f};

    const int ar = t >> 3, ac4 = (t & 7) * 4;
    const int brr = t >> 4, bc4 = (t & 15) * 4;

    for (int kt = 0; kt < 8; ++kt) {
        const int k0 = kt * 32;
        float4 av  = *(const float4*)&X[(size_t)(m0g + ar) * H_ + k0 + ac4];
        float4 bv0 = *(const float4*)&W[(size_t)(k0 + brr)      * H_ + n0g + bc4];
        float4 bv1 = *(const float4*)&W[(size_t)(k0 + brr + 16) * H_ + n0g + bc4];
        *(float4*)&As[ar][ac4] = av;
        *(float4*)&Bs[brr][bc4] = bv0;
        *(float4*)&Bs[brr + 16][bc4] = bv1;
        __syncthreads();
        #pragma unroll
        for (int c = 0; c < 32; ++c) {
            const float a0 = As[tm][c], a1 = As[tm + 1][c];
            const float4 b4 = *(const float4*)&Bs[c][tn];
            acc0[0] += a0 * b4.x; acc0[1] += a0 * b4.y; acc0[2] += a0 * b4.z; acc0[3] += a0 * b4.w;
            acc1[0] += a1 * b4.x; acc1[1] += a1 * b4.y; acc1[2] += a1 * b4.z; acc1[3] += a1 * b4.w;
        }
        __syncthreads();
    }
    const float4 bi = *(const float4*)&bias[n0g + tn];
    float4 o0 = make_float4(acc0[0] + bi.x, acc0[1] + bi.y, acc0[2] + bi.z, acc0[3] + bi.w);
    float4 o1 = make_float4(acc1[0] + bi.x, acc1[1] + bi.y, acc1[2] + bi.z, acc1[3] + bi.w);
    if (z == 1) {
        f16x4 h0 = { (_Float16)o0.x, (_Float16)o0.y, (_Float16)o0.z, (_Float16)o0.w };
        f16x4 h1 = { (_Float16)o1.x, (_Float16)o1.y, (_Float16)o1.z, (_Float16)o1.w };
        *(f16x4*)&Kf[(size_t)(m0g + tm)     * H_ + n0g + tn] = h0;
        *(f16x4*)&Kf[(size_t)(m0g + tm + 1) * H_ + n0g + tn] = h1;
    } else {
        float* Out = (z == 0) ? Qb : Vb;
        *(float4*)&Out[(size_t)(m0g + tm)     * H_ + n0g + tn] = o0;
        *(float4*)&Out[(size_t)(m0g + tm + 1) * H_ + n0g + tn] = o1;
    }
}

// ---------------- Kernel QW: build A matrix per (b,q) ----------------
// A[rowQ][h][0:256]   = f16(qW[h,e]) = f16(sum_d Q[rowQ,h*32+d] * Wr[e,h*32+d])
// A[rowQ][h][256:512] = (e>>5==h) ? f16(Q[rowQ,e]) : 0
__global__ __launch_bounds__(256) void qw_kernel(
    const float* __restrict__ Qb, const float* __restrict__ Wr,
    _Float16* __restrict__ Af)
{
    __shared__ __align__(16) float Qs[16][36];
    const int t = threadIdx.x;                // e index
    const int m0 = blockIdx.x * 16;
    const int h = blockIdx.y;

    float4 wr4[8];
    #pragma unroll
    for (int j = 0; j < 8; ++j)
        wr4[j] = *(const float4*)&Wr[(size_t)t * H_ + h * DH_ + j * 4];

    if (t < 128) {
        const int r = t >> 3, d4 = (t & 7) * 4;
        *(float4*)&Qs[r][d4] = *(const float4*)&Qb[(size_t)(m0 + r) * H_ + h * DH_ + d4];
    }
    __syncthreads();

    const bool own = ((t >> 5) == h);
    #pragma unroll 4
    for (int r = 0; r < 16; ++r) {
        float acc = 0.f;
        #pragma unroll
        for (int j = 0; j < 8; ++j) {
            const float4 qv = *(const float4*)&Qs[r][j * 4];
            acc += qv.x * wr4[j].x + qv.y * wr4[j].y + qv.z * wr4[j].z + qv.w * wr4[j].w;
        }
        _Float16* arow = Af + ((size_t)(m0 + r) * NH_ + h) * 512;
        arow[t] = (_Float16)acc;
        arow[256 + t] = own ? (_Float16)Qs[r][t & 31] : (_Float16)0.0f;
    }
}

// ---------------- Kernel B: MFMA scores + mask + softmax + PV ----------------
// One WG per (b,q); 4 waves. Wave w owns key-tiles kt = w, w+4, ...
// Per tile: stage 16 rpe rows f32->f16 into wave-private swizzled LDS,
// then 16x mfma_f32_16x16x32_f16 (8 steps rpe from LDS, 8 steps K from L2).
__global__ __launch_bounds__(256) void attn_kernel(
    const float* __restrict__ rpe, const _Float16* __restrict__ Af,
    const _Float16* __restrict__ Kf, const float* __restrict__ Vb,
    const int* __restrict__ seq_len, const int* __restrict__ lex_num,
    float* __restrict__ out)
{
    __shared__ float sc[NH_ * PADK];
    __shared__ __align__(16) _Float16 stg[4][16][256];
    const int blk = blockIdx.x;
    const int b = blk / S_;
    const int q = blk - b * S_;
    const int t = threadIdx.x;
    const int lane = t & 63;
    const int wave = t >> 6;
    int limit = seq_len[b] + lex_num[b];
    limit = limit < 0 ? 0 : (limit > S_ ? S_ : limit);
    const size_t rowQ = (size_t)(b * S_ + q);

    if (limit == 0) {
        float acc = 0.f;
        const float* vb = Vb + (size_t)b * S_ * H_ + t;
        for (int k = 0; k < S_; ++k) acc += vb[(size_t)k * H_];
        out[rowQ * H_ + t] = acc * (1.0f / S_);
        return;
    }

    const int r = lane & 15;     // fragment row: A-row (head) for A, key for B/C
    const int g = lane >> 4;     // k-group within fragment

    // ---- hoist A-fragments for all 16 contraction steps (64 VGPR) ----
    f16x8 afrag[16];
    {
        const _Float16* Arow = Af + rowQ * (NH_ * 512) + (size_t)r * 512;
        if (r < NH_) {
            #pragma unroll
            for (int j = 0; j < 16; ++j)
                afrag[j] = *(const f16x8*)(Arow + j * 32 + g * 8);
        } else {
            #pragma unroll
            for (int j = 0; j < 16; ++j)
                afrag[j] = (f16x8){};
        }
    }

    char* myl = (char*)&stg[wave][0][0];
    const int swzr = (r & 7) << 4;
    const float* rpe_base = rpe + rowQ * (size_t)S_ * H_;
    const int ntiles = (limit + 15) >> 4;

    for (int kt = wave; kt < ntiles; kt += 4) {
        const int k0 = kt * 16;
        const float* gsrc = rpe_base + (size_t)k0 * H_;
        // ---- stage 16 rows (f32 -> f16, swizzled) ----
        #pragma unroll
        for (int half = 0; half < 2; ++half) {
            float4 v[8];
            #pragma unroll
            for (int rr = 0; rr < 8; ++rr)
                v[rr] = *(const float4*)&gsrc[(size_t)(half * 8 + rr) * H_ + lane * 4];
            #pragma unroll
            for (int rr = 0; rr < 8; ++rr) {
                const int row = half * 8 + rr;
                f16x4 hv = { (_Float16)v[rr].x, (_Float16)v[rr].y,
                             (_Float16)v[rr].z, (_Float16)v[rr].w };
                *(f16x4*)(myl + row * 512 + ((lane * 8) ^ ((row & 7) << 4))) = hv;
            }
        }
        // ---- MFMA: 8 rpe steps (LDS) + 8 K steps (L2-resident f16) ----
        f32x4 acc = {};
        #pragma unroll
        for (int j = 0; j < 8; ++j) {
            f16x8 bf = *(const f16x8*)(myl + r * 512 + ((j * 64 + g * 16) ^ swzr));
            acc = __builtin_amdgcn_mfma_f32_16x16x32_f16(afrag[j], bf, acc, 0, 0, 0);
        }
        const _Float16* krow = Kf + ((size_t)(b * S_ + k0 + r)) * H_;
        #pragma unroll
        for (int j = 0; j < 8; ++j) {
            f16x8 kf = *(const f16x8*)(krow + j * 32 + g * 8);
            acc = __builtin_amdgcn_mfma_f32_16x16x32_f16(afrag[8 + j], kf, acc, 0, 0, 0);
        }
        // ---- write scores: lanes 0..31 hold heads 0..7 (C: col=lane&15, row=g*4+i) ----
        if (lane < 32) {
            #pragma unroll
            for (int i = 0; i < 4; ++i)
                sc[(g * 4 + i) * PADK + k0 + r] = acc[i];
        }
    }
    __syncthreads();

    // ---- softmax: wave w owns heads 2w, 2w+1 ----
    for (int hh = 0; hh < 2; ++hh) {
        const int h = wave * 2 + hh;
        float s0[6];
        #pragma unroll
        for (int j = 0; j < 6; ++j) {
            const int k = lane + 64 * j;
            s0[j] = (k < limit) ? sc[h * PADK + k] : -1e15f;
        }
        float mx = s0[0];
        #pragma unroll
        for (int j = 1; j < 6; ++j) mx = fmaxf(mx, s0[j]);
        #pragma unroll
        for (int m = 1; m < 64; m <<= 1) mx = fmaxf(mx, __shfl_xor(mx, m, 64));
        float p[6]; float sum = 0.f;
        #pragma unroll
        for (int j = 0; j < 6; ++j) {
            const int k = lane + 64 * j;
            p[j] = (k < limit) ? __expf(s0[j] - mx) : 0.f;
            sum += p[j];
        }
        #pragma unroll
        for (int m = 1; m < 64; m <<= 1) sum += __shfl_xor(sum, m, 64);
        const float inv = 1.0f / sum;
        #pragma unroll
        for (int j = 0; j < 6; ++j) sc[h * PADK + lane + 64 * j] = p[j] * inv;
    }
    __syncthreads();

    // ---- PV: thread t -> (h = t>>5, d = t&31) ----
    {
        const int h = t >> 5;
        const int d = t & 31;
        const float* vcol = Vb + (size_t)b * S_ * H_ + h * DH_ + d;
        const float* prow = &sc[h * PADK];
        float acc = 0.f;
        int k = 0;
        for (; k + 8 <= limit; k += 8) {
            float vv[8], pp[8];
            #pragma unroll
            for (int u = 0; u < 8; ++u) vv[u] = vcol[(size_t)(k + u) * H_];
            #pragma unroll
            for (int u = 0; u < 8; ++u) pp[u] = prow[k + u];
            #pragma unroll
            for (int u = 0; u < 8; ++u) acc += pp[u] * vv[u];
        }
        for (; k < limit; ++k) acc += prow[k] * vcol[(size_t)k * H_];
        out[rowQ * H_ + h * DH_ + d] = acc;
    }
}

extern "C" void kernel_launch(void* const* d_in, const int* in_sizes, int n_in,
                              void* d_out, int out_size, void* d_ws, size_t ws_size,
                              hipStream_t stream)
{
    const float* key   = (const float*)d_in[0];
    const float* query = (const float*)d_in[1];
    const float* value = (const float*)d_in[2];
    const float* rpe   = (const float*)d_in[3];
    const int* seq_len = (const int*)d_in[4];
    const int* lex_num = (const int*)d_in[5];
    const float* Wk = (const float*)d_in[6];
    const float* bk = (const float*)d_in[7];
    const float* Wq = (const float*)d_in[8];
    const float* bq = (const float*)d_in[9];
    const float* Wv = (const float*)d_in[10];
    const float* bv = (const float*)d_in[11];
    const float* Wr = (const float*)d_in[12];
    const float* br = (const float*)d_in[13];
    (void)bk; (void)br;

    const size_t NTOK = (size_t)B_ * S_;          // 1536
    float* w = (float*)d_ws;
    float* Qb = w;                                 // f32 [1536*256]
    float* Vb = Qb + NTOK * H_;                    // f32 [1536*256]
    _Float16* Kf = (_Float16*)(Vb + NTOK * H_);    // f16 [1536*256]
    _Float16* Af = Kf + NTOK * H_;                 // f16 [1536*8*512]

    proj_kernel<<<dim3(48, 4, 3), dim3(256), 0, stream>>>(
        query, key, value, Wq, bq, Wk, bk, Wv, bv, Qb, Kf, Vb);
    qw_kernel<<<dim3(96, 8), dim3(256), 0, stream>>>(Qb, Wr, Af);
    attn_kernel<<<dim3(1536), dim3(256), 0, stream>>>(
        rpe, Af, Kf, Vb, seq_len, lex_num, (float*)d_out);
}